// Round 1
// baseline (213.621 us; speedup 1.0000x reference)
//
#include <hip/hip_runtime.h>

#define HIDDEN 128
#define N_REL 64

// 32 lanes per edge; each lane loads one float4 of uh/vh (128 floats = 32 float4).
// w_relation (64x128 f32 = 32 KB) staged in LDS once per block; grid-stride loop
// with capped grid amortizes the staging.
__global__ __launch_bounds__(256) void distmult_score_kernel(
    const float* __restrict__ uh,
    const float* __restrict__ vh,
    const int*   __restrict__ etypes,
    const float* __restrict__ w_rel,
    float*       __restrict__ out,
    int n_edges)
{
    __shared__ float4 rel_lds[N_REL * (HIDDEN / 4)];   // 2048 float4 = 32 KB

    const float4* w4 = reinterpret_cast<const float4*>(w_rel);
    for (int i = threadIdx.x; i < N_REL * (HIDDEN / 4); i += blockDim.x)
        rel_lds[i] = w4[i];
    __syncthreads();

    const float4* uh4 = reinterpret_cast<const float4*>(uh);
    const float4* vh4 = reinterpret_cast<const float4*>(vh);

    const int lane = threadIdx.x & 31;          // lane within 32-lane group
    const int grp  = threadIdx.x >> 5;          // 8 groups per 256-thread block
    const int groups_per_block = blockDim.x >> 5;
    const int stride = groups_per_block * gridDim.x;

    for (int e = blockIdx.x * groups_per_block + grp; e < n_edges; e += stride) {
        const int r = etypes[e];                // broadcast within group
        const size_t base = (size_t)e * (HIDDEN / 4) + lane;
        float4 u = uh4[base];
        float4 v = vh4[base];
        float4 w = rel_lds[r * (HIDDEN / 4) + lane];

        float p = u.x * v.x * w.x
                + u.y * v.y * w.y
                + u.z * v.z * w.z
                + u.w * v.w * w.w;

        // reduce across the 32-lane group (xor masks 1..16 stay within
        // each aligned 32-lane half of the 64-lane wave)
        p += __shfl_xor(p, 1);
        p += __shfl_xor(p, 2);
        p += __shfl_xor(p, 4);
        p += __shfl_xor(p, 8);
        p += __shfl_xor(p, 16);

        if (lane == 0) out[e] = p;
    }
}

extern "C" void kernel_launch(void* const* d_in, const int* in_sizes, int n_in,
                              void* d_out, int out_size, void* d_ws, size_t ws_size,
                              hipStream_t stream) {
    const float* uh     = (const float*)d_in[0];
    const float* vh     = (const float*)d_in[1];
    const int*   etypes = (const int*)d_in[2];
    const float* w_rel  = (const float*)d_in[3];
    float* out = (float*)d_out;

    const int n_edges = in_sizes[2];            // etypes element count = E

    // Capped grid + grid-stride: keeps LDS staging traffic at 2048*32KB = 64 MB
    // while providing ~32 waves/CU of latency-hiding parallelism.
    const int blocks = 2048;
    distmult_score_kernel<<<blocks, 256, 0, stream>>>(uh, vh, etypes, w_rel, out, n_edges);
}

// Round 2
// 182.367 us; speedup vs baseline: 1.1714x; 1.1714x over previous
//
#include <hip/hip_runtime.h>

#define HIDDEN4 32   // 128 floats = 32 float4 per row

// 8 lanes per edge; each lane accumulates 4 float4 (64 B) of the dot product
// in registers, then a 3-step shuffle reduce. w_relation (32 KB total) is read
// directly from global — it is L2-resident, so LDS staging (and its 64 MB of
// HBM traffic + 32 KB/block occupancy cap) is pure overhead.
__global__ __launch_bounds__(256) void distmult_score_kernel(
    const float* __restrict__ uh,
    const float* __restrict__ vh,
    const int*   __restrict__ etypes,
    const float* __restrict__ w_rel,
    float*       __restrict__ out,
    int n_edges)
{
    const float4* __restrict__ uh4 = reinterpret_cast<const float4*>(uh);
    const float4* __restrict__ vh4 = reinterpret_cast<const float4*>(vh);
    const float4* __restrict__ w4  = reinterpret_cast<const float4*>(w_rel);

    const int lane = threadIdx.x & 7;           // lane within 8-lane group
    const int grp  = threadIdx.x >> 3;          // 32 groups per 256-thread block
    const int gpb  = blockDim.x >> 3;
    const int stride = gpb * gridDim.x;

    for (int e = blockIdx.x * gpb + grp; e < n_edges; e += stride) {
        const int r = etypes[e];                // broadcast within group
        const float4* up = uh4 + (size_t)e * HIDDEN4 + lane;
        const float4* vp = vh4 + (size_t)e * HIDDEN4 + lane;
        const float4* wp = w4  + (size_t)r * HIDDEN4 + lane;

        float p = 0.f;
        #pragma unroll
        for (int k = 0; k < 4; ++k) {           // 12 independent loads in flight
            float4 u = up[8 * k];
            float4 v = vp[8 * k];
            float4 w = wp[8 * k];               // L2-resident (32 KB table)
            p += u.x * v.x * w.x
               + u.y * v.y * w.y
               + u.z * v.z * w.z
               + u.w * v.w * w.w;
        }

        // reduce across the 8-lane group (xor masks 1,2,4 stay in-group)
        p += __shfl_xor(p, 1);
        p += __shfl_xor(p, 2);
        p += __shfl_xor(p, 4);

        if (lane == 0) out[e] = p;
    }
}

extern "C" void kernel_launch(void* const* d_in, const int* in_sizes, int n_in,
                              void* d_out, int out_size, void* d_ws, size_t ws_size,
                              hipStream_t stream) {
    const float* uh     = (const float*)d_in[0];
    const float* vh     = (const float*)d_in[1];
    const int*   etypes = (const int*)d_in[2];
    const float* w_rel  = (const float*)d_in[3];
    float* out = (float*)d_out;

    const int n_edges = in_sizes[2];

    // No LDS -> occupancy is VGPR-bound only (32 waves/CU). 2048 blocks fill
    // the chip (256 CU x 8 resident blocks); grid-stride covers the rest.
    const int blocks = 2048;
    distmult_score_kernel<<<blocks, 256, 0, stream>>>(uh, vh, etypes, w_rel, out, n_edges);
}

// Round 3
// 174.145 us; speedup vs baseline: 1.2267x; 1.0472x over previous
//
#include <hip/hip_runtime.h>

#define HIDDEN4 32   // 128 floats = 32 float4 per row

typedef float f32x4 __attribute__((ext_vector_type(4)));

// 8 lanes per edge; each lane accumulates 4 float4 (64 B) in registers, then a
// 3-step shuffle reduce. w_relation (32 KB) read via normal (cached) loads —
// L2-resident. uh/vh are read-once streams -> nontemporal loads so they don't
// evict the w table from L2. etypes prefetched one grid-stride iteration ahead
// to take the gather-address dependency off the critical path.
__global__ __launch_bounds__(256) void distmult_score_kernel(
    const float* __restrict__ uh,
    const float* __restrict__ vh,
    const int*   __restrict__ etypes,
    const float* __restrict__ w_rel,
    float*       __restrict__ out,
    int n_edges)
{
    const f32x4* __restrict__ uh4 = reinterpret_cast<const f32x4*>(uh);
    const f32x4* __restrict__ vh4 = reinterpret_cast<const f32x4*>(vh);
    const f32x4* __restrict__ w4  = reinterpret_cast<const f32x4*>(w_rel);

    const int lane = threadIdx.x & 7;           // lane within 8-lane group
    const int grp  = threadIdx.x >> 3;          // 32 groups per 256-thread block
    const int gpb  = blockDim.x >> 3;
    const int stride = gpb * gridDim.x;

    int e = blockIdx.x * gpb + grp;
    int r_next = (e < n_edges) ? etypes[e] : 0;

    for (; e < n_edges; e += stride) {
        const int r  = r_next;
        const int en = e + stride;
        if (en < n_edges) r_next = etypes[en];  // prefetch next gather index

        const f32x4* up = uh4 + (size_t)e * HIDDEN4 + lane;
        const f32x4* vp = vh4 + (size_t)e * HIDDEN4 + lane;
        const f32x4* wp = w4  + (size_t)r * HIDDEN4 + lane;

        float p = 0.f;
        #pragma unroll
        for (int k = 0; k < 4; ++k) {
            f32x4 u = __builtin_nontemporal_load(up + 8 * k);  // read-once stream
            f32x4 v = __builtin_nontemporal_load(vp + 8 * k);  // read-once stream
            f32x4 w = wp[8 * k];                               // L2-resident table
            p += u.x * v.x * w.x
               + u.y * v.y * w.y
               + u.z * v.z * w.z
               + u.w * v.w * w.w;
        }

        // reduce across the 8-lane group (xor masks 1,2,4 stay in-group)
        p += __shfl_xor(p, 1);
        p += __shfl_xor(p, 2);
        p += __shfl_xor(p, 4);

        if (lane == 0) __builtin_nontemporal_store(p, out + e);
    }
}

extern "C" void kernel_launch(void* const* d_in, const int* in_sizes, int n_in,
                              void* d_out, int out_size, void* d_ws, size_t ws_size,
                              hipStream_t stream) {
    const float* uh     = (const float*)d_in[0];
    const float* vh     = (const float*)d_in[1];
    const int*   etypes = (const int*)d_in[2];
    const float* w_rel  = (const float*)d_in[3];
    float* out = (float*)d_out;

    const int n_edges = in_sizes[2];

    // 4096 blocks = 2x oversubscription of the 2048-resident capacity: smooths
    // the 15-vs-16-iteration quantization tail that strands ~26% of groups in
    // a low-occupancy final iteration with an exactly-resident grid.
    const int blocks = 4096;
    distmult_score_kernel<<<blocks, 256, 0, stream>>>(uh, vh, etypes, w_rel, out, n_edges);
}

// Round 4
// 166.155 us; speedup vs baseline: 1.2857x; 1.0481x over previous
//
#include <hip/hip_runtime.h>

#define HIDDEN4 32   // 128 floats = 32 float4 per row

typedef float f32x4 __attribute__((ext_vector_type(4)));

// 8 lanes per edge; each lane accumulates 4 float4 (64 B) in registers, then a
// 3-step shuffle reduce. w_relation (32 KB) read via cached loads (L2-resident).
// uh/vh/etypes are read-once streams -> nontemporal. etypes prefetched one
// grid-stride iteration ahead to hide the gather-address dependency.
__global__ __launch_bounds__(256) void distmult_score_kernel(
    const float* __restrict__ uh,
    const float* __restrict__ vh,
    const int*   __restrict__ etypes,
    const float* __restrict__ w_rel,
    float*       __restrict__ out,
    int n_edges)
{
    const f32x4* __restrict__ uh4 = reinterpret_cast<const f32x4*>(uh);
    const f32x4* __restrict__ vh4 = reinterpret_cast<const f32x4*>(vh);
    const f32x4* __restrict__ w4  = reinterpret_cast<const f32x4*>(w_rel);

    const int lane = threadIdx.x & 7;           // lane within 8-lane group
    const int grp  = threadIdx.x >> 3;          // 32 groups per 256-thread block
    const int gpb  = blockDim.x >> 3;
    const int stride = gpb * gridDim.x;

    int e = blockIdx.x * gpb + grp;
    int r_next = (e < n_edges) ? __builtin_nontemporal_load(etypes + e) : 0;

    for (; e < n_edges; e += stride) {
        const int r  = r_next;
        const int en = e + stride;
        if (en < n_edges) r_next = __builtin_nontemporal_load(etypes + en);

        const f32x4* up = uh4 + (size_t)e * HIDDEN4 + lane;
        const f32x4* vp = vh4 + (size_t)e * HIDDEN4 + lane;
        const f32x4* wp = w4  + (size_t)r * HIDDEN4 + lane;

        float p = 0.f;
        #pragma unroll
        for (int k = 0; k < 4; ++k) {
            f32x4 u = __builtin_nontemporal_load(up + 8 * k);  // read-once stream
            f32x4 v = __builtin_nontemporal_load(vp + 8 * k);  // read-once stream
            f32x4 w = wp[8 * k];                               // L2-resident table
            p += u.x * v.x * w.x
               + u.y * v.y * w.y
               + u.z * v.z * w.z
               + u.w * v.w * w.w;
        }

        // reduce across the 8-lane group (xor masks 1,2,4 stay in-group)
        p += __shfl_xor(p, 1);
        p += __shfl_xor(p, 2);
        p += __shfl_xor(p, 4);

        if (lane == 0) __builtin_nontemporal_store(p, out + e);
    }
}

extern "C" void kernel_launch(void* const* d_in, const int* in_sizes, int n_in,
                              void* d_out, int out_size, void* d_ws, size_t ws_size,
                              hipStream_t stream) {
    const float* uh     = (const float*)d_in[0];
    const float* vh     = (const float*)d_in[1];
    const int*   etypes = (const int*)d_in[2];
    const float* w_rel  = (const float*)d_in[3];
    float* out = (float*)d_out;

    const int n_edges = in_sizes[2];

    // 8192 blocks (4x resident capacity): shrinks the grid-stride loop to ~3.8
    // iterations/group, reducing the final-iteration imbalance quantum.
    const int blocks = 8192;
    distmult_score_kernel<<<blocks, 256, 0, stream>>>(uh, vh, etypes, w_rel, out, n_edges);
}